// Round 6
// baseline (121.996 us; speedup 1.0000x reference)
//
#include <hip/hip_runtime.h>
#include <math.h>

#define SELU_SCALE 1.0507009873554805f
#define SELU_ALPHA 1.6732632423543772f

constexpr int CIN  = 3;
constexpr int HH   = 32;
constexpr int WW   = 32;
constexpr int OUTF = 64;
constexpr int NPAIR = 14;   // 27 conv taps + bias-as-tap-27, packed in f16 pairs

typedef _Float16 f16x2 __attribute__((ext_vector_type(2)));

// cvt_pkrtz returns __fp16 ext_vector(2); bit_cast to our f16x2 (round-5 fix).
__device__ __forceinline__ f16x2 pack_f16(float a, float b) {
    return __builtin_bit_cast(f16x2, __builtin_amdgcn_cvt_pkrtz(a, b));
}

// ---- DPP wave64 sum (pure VALU; lane 63 holds the total) ----
template <int CTRL, int ROW_MASK>
__device__ __forceinline__ float dpp_add(float v) {
    int sh = __builtin_amdgcn_update_dpp(0, __float_as_int(v),
                                         CTRL, ROW_MASK, 0xf, false);
    return v + __int_as_float(sh);
}
__device__ __forceinline__ float wave64_sum(float v) {
    v = dpp_add<0x111, 0xf>(v);  // row_shr:1
    v = dpp_add<0x112, 0xf>(v);  // row_shr:2
    v = dpp_add<0x114, 0xf>(v);  // row_shr:4
    v = dpp_add<0x118, 0xf>(v);  // row_shr:8
    v = dpp_add<0x142, 0xa>(v);  // row_bcast:15 -> rows 1,3
    v = dpp_add<0x143, 0xc>(v);  // row_bcast:31 -> rows 2,3
    return v;
}

// Pre-pack weights+bias to f16 pairs: pw[o][t] = (w[2t][o], t<13 ? w[2t+1][o] : bias[o]).
// Runs once per launch (64 threads); main kernel then reads wave-uniform u32 -> s_load.
__global__ void pack_weights(const float* __restrict__ weight,
                             const float* __restrict__ bias,
                             unsigned int* __restrict__ pw) {
    const int o = threadIdx.x;   // 0..63
    #pragma unroll
    for (int t = 0; t < NPAIR; ++t) {
        const float a = weight[(2 * t) * OUTF + o];
        const float b = (t < NPAIR - 1) ? weight[(2 * t + 1) * OUTF + o] : bias[o];
        pw[o * NPAIR + t] = __builtin_bit_cast(unsigned int, pack_f16(a, b));
    }
}

// One block per image n. Thread t owns output row h = t>>3, cols w0..w0+3
// (2 LPPool pairs). Conv = 14 v_dot2_f32_f16 per position from a packed-f16
// register window (56 half2 regs, built once) — halves conv issue slots vs
// f32 FMA, and kills the round-4 LDS re-read demotion (window is 56 VGPRs).
__global__ __launch_bounds__(256, 4) void fused_conv_selu_pool(
    const float* __restrict__ x,            // (1024, 3, 32, 32)
    const unsigned int* __restrict__ pw,    // (64, 14) packed f16 weight pairs
    const float* __restrict__ scale_proj,   // (3, 64)
    const float* __restrict__ scale_bias,   // (64,)
    float* __restrict__ out)                // (1024, 64)
{
    const int n    = blockIdx.x;
    const int t    = threadIdx.x;
    const int lane = t & 63;
    const int wave = t >> 6;

    __shared__ float xs[CIN][34][34];   // zero-padded input tile, 13.9 KB
    __shared__ float red[4][OUTF];      // per-wave pooled partials
    __shared__ float credu[CIN][4];     // per-wave channel-sum partials

    // ---- zero the padded tile ----
    float* xsf = &xs[0][0][0];
    for (int i = t; i < CIN * 34 * 34; i += 256) xsf[i] = 0.f;
    __syncthreads();

    // ---- load x[n] into LDS interior + per-channel sums ----
    const float* xn = x + (size_t)n * (CIN * HH * WW);
    float cp0 = 0.f, cp1 = 0.f, cp2 = 0.f;
    for (int i = t; i < CIN * HH * WW; i += 256) {  // 12 iters, coalesced
        float v  = xn[i];
        int   c  = i >> 10;       // H*W = 1024
        int   hw = i & 1023;
        xs[c][(hw >> 5) + 1][(hw & 31) + 1] = v;
        if (c == 0) cp0 += v; else if (c == 1) cp1 += v; else cp2 += v;
    }
    cp0 = wave64_sum(cp0);
    cp1 = wave64_sum(cp1);
    cp2 = wave64_sum(cp2);
    if (lane == 63) { credu[0][wave] = cp0; credu[1][wave] = cp1; credu[2][wave] = cp2; }
    __syncthreads();

    // ---- build packed-f16 window: xp[t][p] = (win[2t][p], win[2t+1][p]) ----
    // win[k][p] = xs[c][h+ki][w0+kj+p], k=c*9+ki*3+kj; k=27 is the bias tap (=1).
    const int h  = t >> 3;          // 0..31
    const int w0 = (t & 7) << 2;    // 0,4,...,28
    f16x2 xp[NPAIR][4];
    #pragma unroll
    for (int tp = 0; tp < NPAIR; ++tp) {
        const int k0 = 2 * tp, k1 = 2 * tp + 1;
        const int c0 = k0 / 9, r0 = (k0 % 9) / 3, j0 = k0 % 3;
        const int c1 = k1 / 9, r1 = (k1 % 9) / 3, j1 = k1 % 3;
        #pragma unroll
        for (int p = 0; p < 4; ++p) {
            const float a = xs[c0][h + r0][w0 + j0 + p];
            const float b = (tp < NPAIR - 1) ? xs[c1][h + r1][w0 + j1 + p] : 1.0f;
            xp[tp][p] = pack_f16(a, b);
        }
    }

    // ---- conv (dot2) + SELU + LPPool + DPP wave reduce, per channel ----
    // SELU_SCALE hoisted (commutes through 2-norm pool and mean).
    #pragma unroll 4
    for (int o = 0; o < OUTF; ++o) {
        const unsigned int* pwo = pw + o * NPAIR;  // wave-uniform -> s_load
        float s0 = 0.f, s1 = 0.f, s2 = 0.f, s3 = 0.f;
        #pragma unroll
        for (int tp = 0; tp < NPAIR; ++tp) {
            const f16x2 wv = __builtin_bit_cast(f16x2, pwo[tp]);
            s0 = __builtin_amdgcn_fdot2(xp[tp][0], wv, s0, false);
            s1 = __builtin_amdgcn_fdot2(xp[tp][1], wv, s1, false);
            s2 = __builtin_amdgcn_fdot2(xp[tp][2], wv, s2, false);
            s3 = __builtin_amdgcn_fdot2(xp[tp][3], wv, s3, false);
        }
        // SELU without the outer scale
        s0 = s0 > 0.f ? s0 : SELU_ALPHA * (__expf(s0) - 1.f);
        s1 = s1 > 0.f ? s1 : SELU_ALPHA * (__expf(s1) - 1.f);
        s2 = s2 > 0.f ? s2 : SELU_ALPHA * (__expf(s2) - 1.f);
        s3 = s3 > 0.f ? s3 : SELU_ALPHA * (__expf(s3) - 1.f);
        // LPPool over the two w-pairs, then DPP-reduce this channel
        float r = __builtin_amdgcn_sqrtf(fmaf(s0, s0, s1 * s1))
                + __builtin_amdgcn_sqrtf(fmaf(s2, s2, s3 * s3));
        r = wave64_sum(r);
        if (lane == 63) red[wave][o] = r;
    }
    __syncthreads();

    // ---- gate + store ----
    if (t < OUTF) {
        const float s    = red[0][t] + red[1][t] + red[2][t] + red[3][t];
        const float mean = s * (SELU_SCALE / 512.f);   // 32*16 pooled elems
        float g = scale_bias[t];
        #pragma unroll
        for (int c = 0; c < CIN; ++c) {
            const float cs = (credu[c][0] + credu[c][1] + credu[c][2] + credu[c][3])
                             * (1.f / 1024.f);
            g = fmaf(cs, scale_proj[c * 64 + t], g);
        }
        g = 1.f / (1.f + __expf(-g));
        out[(size_t)n * OUTF + t] = mean * g;
    }
}

extern "C" void kernel_launch(void* const* d_in, const int* in_sizes, int n_in,
                              void* d_out, int out_size, void* d_ws, size_t ws_size,
                              hipStream_t stream) {
    const float* x          = (const float*)d_in[0];
    const float* weight     = (const float*)d_in[1];
    const float* bias       = (const float*)d_in[2];
    const float* scale_proj = (const float*)d_in[3];
    const float* scale_bias = (const float*)d_in[4];
    float* out = (float*)d_out;
    unsigned int* pw = (unsigned int*)d_ws;   // 64*14*4 = 3.5 KB scratch

    pack_weights<<<1, OUTF, 0, stream>>>(weight, bias, pw);
    fused_conv_selu_pool<<<1024, 256, 0, stream>>>(x, pw, scale_proj,
                                                   scale_bias, out);
}

// Round 7
// 121.717 us; speedup vs baseline: 1.0023x; 1.0023x over previous
//
#include <hip/hip_runtime.h>
#include <math.h>

#define SELU_SCALE 1.0507009873554805f
#define SELU_ALPHA 1.6732632423543772f

constexpr int CIN  = 3;
constexpr int HH   = 32;
constexpr int WW   = 32;
constexpr int OUTF = 64;
constexpr int NPAIR = 14;   // 27 conv taps + bias-as-tap-27, packed in f16 pairs

typedef _Float16 f16x2 __attribute__((ext_vector_type(2)));

__device__ __forceinline__ f16x2 pack_f16(float a, float b) {
    return __builtin_bit_cast(f16x2, __builtin_amdgcn_cvt_pkrtz(a, b));
}

// ---- DPP wave64 sum (pure VALU; lane 63 holds the total) ----
template <int CTRL, int ROW_MASK>
__device__ __forceinline__ float dpp_add(float v) {
    int sh = __builtin_amdgcn_update_dpp(0, __float_as_int(v),
                                         CTRL, ROW_MASK, 0xf, false);
    return v + __int_as_float(sh);
}
__device__ __forceinline__ float wave64_sum(float v) {
    v = dpp_add<0x111, 0xf>(v);  // row_shr:1
    v = dpp_add<0x112, 0xf>(v);  // row_shr:2
    v = dpp_add<0x114, 0xf>(v);  // row_shr:4
    v = dpp_add<0x118, 0xf>(v);  // row_shr:8
    v = dpp_add<0x142, 0xa>(v);  // row_bcast:15 -> rows 1,3
    v = dpp_add<0x143, 0xc>(v);  // row_bcast:31 -> rows 2,3
    return v;
}

// Pre-pack weights+bias to f16 pairs: pw[o][t] = (w[2t][o], t<13 ? w[2t+1][o] : bias[o]).
__global__ void pack_weights(const float* __restrict__ weight,
                             const float* __restrict__ bias,
                             unsigned int* __restrict__ pw) {
    const int o = threadIdx.x;   // 0..63
    #pragma unroll
    for (int t = 0; t < NPAIR; ++t) {
        const float a = weight[(2 * t) * OUTF + o];
        const float b = (t < NPAIR - 1) ? weight[(2 * t + 1) * OUTF + o] : bias[o];
        pw[o * NPAIR + t] = __builtin_bit_cast(unsigned int, pack_f16(a, b));
    }
}

// One block per image n. Thread t owns output row h = t>>3, cols w0..w0+3
// (2 LPPool pairs). Conv = 14 v_dot2_f32_f16 per position from a packed-f16
// register window. Round-6 lesson: the allocator remats the window from LDS
// (VGPR=36, 56 ds_read per o-iter) — so each window dword is pinned in a
// VGPR with an opaque empty asm, which cannot be rematerialized.
__global__ __launch_bounds__(256, 4) void fused_conv_selu_pool(
    const float* __restrict__ x,            // (1024, 3, 32, 32)
    const unsigned int* __restrict__ pw,    // (64, 14) packed f16 weight pairs
    const float* __restrict__ scale_proj,   // (3, 64)
    const float* __restrict__ scale_bias,   // (64,)
    float* __restrict__ out)                // (1024, 64)
{
    const int n    = blockIdx.x;
    const int t    = threadIdx.x;
    const int lane = t & 63;
    const int wave = t >> 6;

    __shared__ float xs[CIN][34][34];   // zero-padded input tile, 13.9 KB
    __shared__ float red[4][OUTF];      // per-wave pooled partials
    __shared__ float credu[CIN][4];     // per-wave channel-sum partials

    // ---- zero the padded tile ----
    float* xsf = &xs[0][0][0];
    for (int i = t; i < CIN * 34 * 34; i += 256) xsf[i] = 0.f;
    __syncthreads();

    // ---- load x[n] into LDS interior + per-channel sums ----
    const float* xn = x + (size_t)n * (CIN * HH * WW);
    float cp0 = 0.f, cp1 = 0.f, cp2 = 0.f;
    for (int i = t; i < CIN * HH * WW; i += 256) {  // 12 iters, coalesced
        float v  = xn[i];
        int   c  = i >> 10;       // H*W = 1024
        int   hw = i & 1023;
        xs[c][(hw >> 5) + 1][(hw & 31) + 1] = v;
        if (c == 0) cp0 += v; else if (c == 1) cp1 += v; else cp2 += v;
    }
    cp0 = wave64_sum(cp0);
    cp1 = wave64_sum(cp1);
    cp2 = wave64_sum(cp2);
    if (lane == 63) { credu[0][wave] = cp0; credu[1][wave] = cp1; credu[2][wave] = cp2; }
    __syncthreads();

    // ---- build packed-f16 window: xp[t][p] = (win[2t][p], win[2t+1][p]) ----
    // win[k][p] = xs[c][h+ki][w0+kj+p], k=c*9+ki*3+kj; k=27 is the bias tap (=1).
    const int h  = t >> 3;          // 0..31
    const int w0 = (t & 7) << 2;    // 0,4,...,28
    unsigned int xp[NPAIR][4];
    #pragma unroll
    for (int tp = 0; tp < NPAIR; ++tp) {
        const int k0 = 2 * tp, k1 = 2 * tp + 1;
        const int c0 = k0 / 9, r0 = (k0 % 9) / 3, j0 = k0 % 3;
        const int c1 = k1 / 9, r1 = (k1 % 9) / 3, j1 = k1 % 3;
        #pragma unroll
        for (int p = 0; p < 4; ++p) {
            const float a = xs[c0][h + r0][w0 + j0 + p];
            const float b = (tp < NPAIR - 1) ? xs[c1][h + r1][w0 + j1 + p] : 1.0f;
            xp[tp][p] = __builtin_bit_cast(unsigned int, pack_f16(a, b));
        }
    }
    // Pin every window dword in a VGPR: opaque def -> no LDS remat possible.
    #pragma unroll
    for (int tp = 0; tp < NPAIR; ++tp)
        #pragma unroll
        for (int p = 0; p < 4; ++p)
            asm volatile("" : "+v"(xp[tp][p]));

    // ---- conv (dot2) + SELU + LPPool + DPP wave reduce, per channel ----
    // SELU_SCALE hoisted (commutes through 2-norm pool and mean).
    #pragma unroll 4
    for (int o = 0; o < OUTF; ++o) {
        const unsigned int* pwo = pw + o * NPAIR;  // wave-uniform -> s_load
        float s0 = 0.f, s1 = 0.f, s2 = 0.f, s3 = 0.f;
        #pragma unroll
        for (int tp = 0; tp < NPAIR; ++tp) {
            const f16x2 wv = __builtin_bit_cast(f16x2, pwo[tp]);
            s0 = __builtin_amdgcn_fdot2(__builtin_bit_cast(f16x2, xp[tp][0]), wv, s0, false);
            s1 = __builtin_amdgcn_fdot2(__builtin_bit_cast(f16x2, xp[tp][1]), wv, s1, false);
            s2 = __builtin_amdgcn_fdot2(__builtin_bit_cast(f16x2, xp[tp][2]), wv, s2, false);
            s3 = __builtin_amdgcn_fdot2(__builtin_bit_cast(f16x2, xp[tp][3]), wv, s3, false);
        }
        // SELU without the outer scale
        s0 = s0 > 0.f ? s0 : SELU_ALPHA * (__expf(s0) - 1.f);
        s1 = s1 > 0.f ? s1 : SELU_ALPHA * (__expf(s1) - 1.f);
        s2 = s2 > 0.f ? s2 : SELU_ALPHA * (__expf(s2) - 1.f);
        s3 = s3 > 0.f ? s3 : SELU_ALPHA * (__expf(s3) - 1.f);
        // LPPool over the two w-pairs, then DPP-reduce this channel
        float r = __builtin_amdgcn_sqrtf(fmaf(s0, s0, s1 * s1))
                + __builtin_amdgcn_sqrtf(fmaf(s2, s2, s3 * s3));
        r = wave64_sum(r);
        if (lane == 63) red[wave][o] = r;
    }
    __syncthreads();

    // ---- gate + store ----
    if (t < OUTF) {
        const float s    = red[0][t] + red[1][t] + red[2][t] + red[3][t];
        const float mean = s * (SELU_SCALE / 512.f);   // 32*16 pooled elems
        float g = scale_bias[t];
        #pragma unroll
        for (int c = 0; c < CIN; ++c) {
            const float cs = (credu[c][0] + credu[c][1] + credu[c][2] + credu[c][3])
                             * (1.f / 1024.f);
            g = fmaf(cs, scale_proj[c * 64 + t], g);
        }
        g = 1.f / (1.f + __expf(-g));
        out[(size_t)n * OUTF + t] = mean * g;
    }
}

extern "C" void kernel_launch(void* const* d_in, const int* in_sizes, int n_in,
                              void* d_out, int out_size, void* d_ws, size_t ws_size,
                              hipStream_t stream) {
    const float* x          = (const float*)d_in[0];
    const float* weight     = (const float*)d_in[1];
    const float* bias       = (const float*)d_in[2];
    const float* scale_proj = (const float*)d_in[3];
    const float* scale_bias = (const float*)d_in[4];
    float* out = (float*)d_out;
    unsigned int* pw = (unsigned int*)d_ws;   // 64*14*4 = 3.5 KB scratch

    pack_weights<<<1, OUTF, 0, stream>>>(weight, bias, pw);
    fused_conv_selu_pool<<<1024, 256, 0, stream>>>(x, pw, scale_proj,
                                                   scale_bias, out);
}

// Round 8
// 91.149 us; speedup vs baseline: 1.3384x; 1.3354x over previous
//
#include <hip/hip_runtime.h>
#include <math.h>

#define SELU_SCALE 1.0507009873554805f
#define SELU_ALPHA 1.6732632423543772f

constexpr int CIN  = 3;
constexpr int HH   = 32;
constexpr int WW   = 32;
constexpr int OUTF = 64;

typedef _Float16 f16x8 __attribute__((ext_vector_type(8)));
typedef _Float16 f16x2 __attribute__((ext_vector_type(2)));
typedef float    f32x4 __attribute__((ext_vector_type(4)));

__device__ __forceinline__ unsigned int pack2(float a, float b) {
    return __builtin_bit_cast(unsigned int, __builtin_amdgcn_cvt_pkrtz(a, b));
}

// ---- DPP wave64 sum (stage-1 channel sums; lane 63 holds total) ----
template <int CTRL, int ROW_MASK>
__device__ __forceinline__ float dpp_add(float v) {
    int sh = __builtin_amdgcn_update_dpp(0, __float_as_int(v),
                                         CTRL, ROW_MASK, 0xf, false);
    return v + __int_as_float(sh);
}
__device__ __forceinline__ float wave64_sum(float v) {
    v = dpp_add<0x111, 0xf>(v);
    v = dpp_add<0x112, 0xf>(v);
    v = dpp_add<0x114, 0xf>(v);
    v = dpp_add<0x118, 0xf>(v);
    v = dpp_add<0x142, 0xa>(v);  // row_bcast:15
    v = dpp_add<0x143, 0xc>(v);  // row_bcast:31
    return v;
}

__device__ __forceinline__ float selu_ns(float s) {  // SELU without outer scale
    float e = SELU_ALPHA * (__expf(s) - 1.f);
    return s > 0.f ? s : e;
}

// Pre-pack weights into MFMA B-operand fragments (f16).
// B[k][n]: lane holds n = lane&15 (oc within tile), k = (lane>>4)*8 + j.
// w_eff[k][oc] = weight[k][oc] for k<27, bias[oc] for k==27, 0 for k>27.
// pwB[ot*64 + lane] = uint4{ pack(w_eff[k0+2r], w_eff[k0+2r+1]) : r=0..3 }.
__global__ void pack_weights(const float* __restrict__ weight,
                             const float* __restrict__ bias,
                             uint4* __restrict__ pwB) {
    const int t    = threadIdx.x;      // 0..255
    const int ot   = t >> 6;           // oc tile 0..3
    const int lane = t & 63;
    const int oc   = ot * 16 + (lane & 15);
    const int k0   = (lane >> 4) * 8;
    unsigned int d[4];
    #pragma unroll
    for (int r = 0; r < 4; ++r) {
        const int ka = k0 + 2 * r, kb = ka + 1;
        const float wa = (ka < 27) ? weight[ka * OUTF + oc] : (ka == 27 ? bias[oc] : 0.f);
        const float wb = (kb < 27) ? weight[kb * OUTF + oc] : (kb == 27 ? bias[oc] : 0.f);
        d[r] = pack2(wa, wb);
    }
    pwB[ot * 64 + lane] = make_uint4(d[0], d[1], d[2], d[3]);
}

// One block per image. 4 waves; wave w owns 16 position-tiles (16 consecutive
// w-positions each). Per tile: each lane reads its 8 patch taps from xs ONCE,
// packs f16 A-frag, 4x mfma_f32_16x16x32_f16 vs weight B-frags.
// C layout (m89): col=lane&15 -> oc-within-tile, row=(lane>>4)*4+i -> position.
// So LPPool pairs are (d[0],d[1]),(d[2],d[3]) intra-lane. Rounds 4-7 lesson:
// per-channel register windows get rematerialized from LDS (1792 ds_read/thr,
// LDS-issue-bound at 65us) — this structure reads LDS ~128x less by design.
__global__ __launch_bounds__(256, 4) void fused_conv_mfma(
    const float* __restrict__ x,            // (1024, 3, 32, 32)
    const uint4* __restrict__ pwB,          // (4, 64) packed B fragments
    const float* __restrict__ scale_proj,   // (3, 64)
    const float* __restrict__ scale_bias,   // (64,)
    float* __restrict__ out)                // (1024, 64)
{
    const int n    = blockIdx.x;
    const int t    = threadIdx.x;
    const int lane = t & 63;
    const int wv   = t >> 6;
    const int quad = lane >> 4;
    const int m16  = lane & 15;

    __shared__ float xs[CIN][34][34];   // zero-padded input tile, 13.9 KB
    __shared__ float red4[4][4][OUTF];  // per-wave, per-quad pooled partials, 4 KB
    __shared__ float credu[CIN][4];

    // ---- zero the padded tile ----
    float* xsf = &xs[0][0][0];
    for (int i = t; i < CIN * 34 * 34; i += 256) xsf[i] = 0.f;
    __syncthreads();

    // ---- load x[n] into LDS interior + per-channel sums ----
    const float* xn = x + (size_t)n * (CIN * HH * WW);
    float cp0 = 0.f, cp1 = 0.f, cp2 = 0.f;
    for (int i = t; i < CIN * HH * WW; i += 256) {
        float v  = xn[i];
        int   c  = i >> 10;
        int   hw = i & 1023;
        xs[c][(hw >> 5) + 1][(hw & 31) + 1] = v;
        if (c == 0) cp0 += v; else if (c == 1) cp1 += v; else cp2 += v;
    }
    cp0 = wave64_sum(cp0);
    cp1 = wave64_sum(cp1);
    cp2 = wave64_sum(cp2);
    if (lane == 63) { credu[0][wv] = cp0; credu[1][wv] = cp1; credu[2][wv] = cp2; }
    __syncthreads();

    // ---- weight B-fragments (global, L1-hot, lane-indexed) ----
    f16x8 bfr[4];
    #pragma unroll
    for (int ot = 0; ot < 4; ++ot)
        bfr[ot] = __builtin_bit_cast(f16x8, pwB[ot * 64 + lane]);

    // ---- per-lane tap offsets (element offsets into xs, constant per lane) ----
    // tap k = quad*8 + j -> (c,rr,cc); loff = c*34*34 + rr*34 + cc + m16.
    int loff[8];
    #pragma unroll
    for (int j = 0; j < 8; ++j) {
        const int k  = quad * 8 + j;
        const int c  = (k >= 18) ? 2 : (k >= 9 ? 1 : 0);
        const int rm = k - 9 * c;
        const int rr = (rm >= 6) ? 2 : (rm >= 3 ? 1 : 0);
        const int cc = rm - 3 * rr;
        loff[j] = (k < 27) ? (c * 1156 + rr * 34 + cc + m16) : m16;
    }
    const bool g3 = (quad == 3);

    // ---- main loop: 16 position-tiles per wave ----
    float racc[4] = {0.f, 0.f, 0.f, 0.f};
    const int tile0 = wv * 16;
    const f32x4 zc = {0.f, 0.f, 0.f, 0.f};
    for (int jt = 0; jt < 16; ++jt) {
        const int tile  = tile0 + jt;
        const int sbase = (tile >> 1) * 34 + (tile & 1) * 16;  // row h, wbase

        float v[8];
        #pragma unroll
        for (int j = 0; j < 8; ++j) v[j] = xsf[sbase + loff[j]];
        // quad 3: j=3 is the bias tap (patch value 1), j>=4 are K-padding (0)
        v[3] = g3 ? 1.0f : v[3];
        v[4] = g3 ? 0.0f : v[4];
        v[5] = g3 ? 0.0f : v[5];
        v[6] = g3 ? 0.0f : v[6];
        v[7] = g3 ? 0.0f : v[7];

        uint4 au = make_uint4(pack2(v[0], v[1]), pack2(v[2], v[3]),
                              pack2(v[4], v[5]), pack2(v[6], v[7]));
        const f16x8 af = __builtin_bit_cast(f16x8, au);

        #pragma unroll
        for (int ot = 0; ot < 4; ++ot) {
            f32x4 d = __builtin_amdgcn_mfma_f32_16x16x32_f16(af, bfr[ot], zc, 0, 0, 0);
            const float s0 = selu_ns(d[0]);
            const float s1 = selu_ns(d[1]);
            const float s2 = selu_ns(d[2]);
            const float s3 = selu_ns(d[3]);
            racc[ot] += __builtin_amdgcn_sqrtf(fmaf(s0, s0, s1 * s1))
                      + __builtin_amdgcn_sqrtf(fmaf(s2, s2, s3 * s3));
        }
    }

    // ---- stash per-(wave,quad) partials; all 64 lanes write distinct slots ----
    #pragma unroll
    for (int ot = 0; ot < 4; ++ot)
        red4[wv][quad][ot * 16 + m16] = racc[ot];
    __syncthreads();

    // ---- gate + store ----
    if (t < OUTF) {
        float s = 0.f;
        #pragma unroll
        for (int w = 0; w < 4; ++w)
            #pragma unroll
            for (int q = 0; q < 4; ++q)
                s += red4[w][q][t];
        const float mean = s * (SELU_SCALE / 512.f);   // 32*16 pooled elems
        float g = scale_bias[t];
        #pragma unroll
        for (int c = 0; c < CIN; ++c) {
            const float cs = (credu[c][0] + credu[c][1] + credu[c][2] + credu[c][3])
                             * (1.f / 1024.f);
            g = fmaf(cs, scale_proj[c * OUTF + t], g);
        }
        g = 1.f / (1.f + __expf(-g));
        out[(size_t)n * OUTF + t] = mean * g;
    }
}

extern "C" void kernel_launch(void* const* d_in, const int* in_sizes, int n_in,
                              void* d_out, int out_size, void* d_ws, size_t ws_size,
                              hipStream_t stream) {
    const float* x          = (const float*)d_in[0];
    const float* weight     = (const float*)d_in[1];
    const float* bias       = (const float*)d_in[2];
    const float* scale_proj = (const float*)d_in[3];
    const float* scale_bias = (const float*)d_in[4];
    float* out = (float*)d_out;
    uint4* pwB = (uint4*)d_ws;   // 4*64*16 = 4 KB scratch

    pack_weights<<<1, 256, 0, stream>>>(weight, bias, pwB);
    fused_conv_mfma<<<1024, 256, 0, stream>>>(x, pwB, scale_proj,
                                              scale_bias, out);
}

// Round 9
// 88.746 us; speedup vs baseline: 1.3747x; 1.0271x over previous
//
#include <hip/hip_runtime.h>
#include <math.h>

#define SELU_SCALE 1.0507009873554805f
#define SELU_ALPHA 1.6732632423543772f

constexpr int CIN  = 3;
constexpr int HH   = 32;
constexpr int WW   = 32;
constexpr int OUTF = 64;

typedef _Float16 f16x8 __attribute__((ext_vector_type(8)));
typedef float    f32x4 __attribute__((ext_vector_type(4)));

__device__ __forceinline__ unsigned int pack2(float a, float b) {
    return __builtin_bit_cast(unsigned int, __builtin_amdgcn_cvt_pkrtz(a, b));
}

// ---- DPP wave64 sum (stage-1 channel sums; lane 63 holds total) ----
template <int CTRL, int ROW_MASK>
__device__ __forceinline__ float dpp_add(float v) {
    int sh = __builtin_amdgcn_update_dpp(0, __float_as_int(v),
                                         CTRL, ROW_MASK, 0xf, false);
    return v + __int_as_float(sh);
}
__device__ __forceinline__ float wave64_sum(float v) {
    v = dpp_add<0x111, 0xf>(v);
    v = dpp_add<0x112, 0xf>(v);
    v = dpp_add<0x114, 0xf>(v);
    v = dpp_add<0x118, 0xf>(v);
    v = dpp_add<0x142, 0xa>(v);  // row_bcast:15
    v = dpp_add<0x143, 0xc>(v);  // row_bcast:31
    return v;
}

__device__ __forceinline__ float selu_ns(float s) {  // SELU without outer scale
    float e = SELU_ALPHA * (__expf(s) - 1.f);
    return s > 0.f ? s : e;
}

// One block per image. 4 waves; wave owns 16 position-tiles of 16 positions.
// Implicit-GEMM via mfma_f32_16x16x32_f16: A = patches (lane m16 = position,
// quad*8+j = tap k), B = weights (packed in-block into LDS; k>=27 rows are 0),
// C = bias broadcast (col=oc). C layout: col=lane&15 -> oc, row=quad*4+i ->
// position, so LPPool pairs (d0,d1),(d2,d3) are intra-lane.
// Round-9 changes vs round-8: bias moved to the C operand (quad-3 A-values
// are don't-care x0 weights -> 5 cndmask/tile deleted), weight packing folded
// into the block (no separate launch, no d_ws), MFMA burst split from the
// SELU epilogue for trans-pipe ILP.
__global__ __launch_bounds__(256, 4) void fused_conv_mfma(
    const float* __restrict__ x,            // (1024, 3, 32, 32)
    const float* __restrict__ weight,       // (27, 64)
    const float* __restrict__ bias,         // (64,)
    const float* __restrict__ scale_proj,   // (3, 64)
    const float* __restrict__ scale_bias,   // (64,)
    float* __restrict__ out)                // (1024, 64)
{
    const int n    = blockIdx.x;
    const int t    = threadIdx.x;
    const int lane = t & 63;
    const int wv   = t >> 6;
    const int quad = lane >> 4;
    const int m16  = lane & 15;

    __shared__ float xs[CIN][34][34];   // zero-padded input tile, 13.9 KB
    __shared__ uint4 wfrag[4][64];      // packed B fragments, 4 KB
    __shared__ float red4[4][4][OUTF];  // per-(wave,quad) pooled partials, 4 KB
    __shared__ float credu[CIN][4];

    // ---- zero the padded tile ----
    float* xsf = &xs[0][0][0];
    for (int i = t; i < CIN * 34 * 34; i += 256) xsf[i] = 0.f;

    // ---- pack this block's B fragments (thread t -> wfrag[t>>6][t&63]) ----
    {
        const int ot = t >> 6, ln = t & 63;
        const int oc = ot * 16 + (ln & 15);
        const int k0 = (ln >> 4) * 8;
        unsigned int d[4];
        #pragma unroll
        for (int r = 0; r < 4; ++r) {
            const int ka = k0 + 2 * r, kb = ka + 1;
            const float wa = (ka < 27) ? weight[ka * OUTF + oc] : 0.f;
            const float wb = (kb < 27) ? weight[kb * OUTF + oc] : 0.f;
            d[r] = pack2(wa, wb);
        }
        wfrag[ot][ln] = make_uint4(d[0], d[1], d[2], d[3]);
    }
    __syncthreads();

    // ---- load x[n] into LDS interior + per-channel sums ----
    const float* xn = x + (size_t)n * (CIN * HH * WW);
    float cp0 = 0.f, cp1 = 0.f, cp2 = 0.f;
    for (int i = t; i < CIN * HH * WW; i += 256) {
        float v  = xn[i];
        int   c  = i >> 10;
        int   hw = i & 1023;
        xs[c][(hw >> 5) + 1][(hw & 31) + 1] = v;
        if (c == 0) cp0 += v; else if (c == 1) cp1 += v; else cp2 += v;
    }
    cp0 = wave64_sum(cp0);
    cp1 = wave64_sum(cp1);
    cp2 = wave64_sum(cp2);
    if (lane == 63) { credu[0][wv] = cp0; credu[1][wv] = cp1; credu[2][wv] = cp2; }
    __syncthreads();

    // ---- B fragments + bias C operand (registers) ----
    f16x8 bfr[4];
    f32x4 cb[4];
    #pragma unroll
    for (int ot = 0; ot < 4; ++ot) {
        bfr[ot] = __builtin_bit_cast(f16x8, wfrag[ot][lane]);
        const float b = bias[ot * 16 + m16];
        cb[ot] = (f32x4){b, b, b, b};
    }

    // ---- per-lane tap offsets (k>=27: any valid addr — weight is 0) ----
    int loff[8];
    #pragma unroll
    for (int j = 0; j < 8; ++j) {
        const int k  = quad * 8 + j;
        const int c  = (k >= 18) ? 2 : (k >= 9 ? 1 : 0);
        const int rm = k - 9 * c;
        const int rr = (rm >= 6) ? 2 : (rm >= 3 ? 1 : 0);
        const int cc = rm - 3 * rr;
        loff[j] = (k < 27) ? (c * 1156 + rr * 34 + cc + m16) : m16;
    }

    // ---- main loop: 16 position-tiles per wave ----
    float racc[4] = {0.f, 0.f, 0.f, 0.f};
    const int tile0 = wv * 16;
    #pragma unroll 2
    for (int jt = 0; jt < 16; ++jt) {
        const int tile  = tile0 + jt;
        const int sbase = (tile >> 1) * 34 + (tile & 1) * 16;  // row h, wbase

        float v[8];
        #pragma unroll
        for (int j = 0; j < 8; ++j) v[j] = xsf[sbase + loff[j]];

        uint4 au = make_uint4(pack2(v[0], v[1]), pack2(v[2], v[3]),
                              pack2(v[4], v[5]), pack2(v[6], v[7]));
        const f16x8 af = __builtin_bit_cast(f16x8, au);

        // MFMA burst (independent), then epilogue — trans-pipe ILP
        f32x4 dd[4];
        #pragma unroll
        for (int ot = 0; ot < 4; ++ot)
            dd[ot] = __builtin_amdgcn_mfma_f32_16x16x32_f16(af, bfr[ot], cb[ot], 0, 0, 0);

        float s[16];
        #pragma unroll
        for (int ot = 0; ot < 4; ++ot) {
            s[4 * ot + 0] = selu_ns(dd[ot][0]);
            s[4 * ot + 1] = selu_ns(dd[ot][1]);
            s[4 * ot + 2] = selu_ns(dd[ot][2]);
            s[4 * ot + 3] = selu_ns(dd[ot][3]);
        }
        #pragma unroll
        for (int ot = 0; ot < 4; ++ot) {
            racc[ot] += __builtin_amdgcn_sqrtf(fmaf(s[4*ot+0], s[4*ot+0], s[4*ot+1] * s[4*ot+1]))
                      + __builtin_amdgcn_sqrtf(fmaf(s[4*ot+2], s[4*ot+2], s[4*ot+3] * s[4*ot+3]));
        }
    }

    // ---- stash per-(wave,quad) partials; all 64 lanes write distinct slots ----
    #pragma unroll
    for (int ot = 0; ot < 4; ++ot)
        red4[wv][quad][ot * 16 + m16] = racc[ot];
    __syncthreads();

    // ---- gate + store ----
    if (t < OUTF) {
        float s = 0.f;
        #pragma unroll
        for (int w = 0; w < 4; ++w)
            #pragma unroll
            for (int q = 0; q < 4; ++q)
                s += red4[w][q][t];
        const float mean = s * (SELU_SCALE / 512.f);   // 32*16 pooled elems
        float g = scale_bias[t];
        #pragma unroll
        for (int c = 0; c < CIN; ++c) {
            const float cs = (credu[c][0] + credu[c][1] + credu[c][2] + credu[c][3])
                             * (1.f / 1024.f);
            g = fmaf(cs, scale_proj[c * OUTF + t], g);
        }
        g = 1.f / (1.f + __expf(-g));
        out[(size_t)n * OUTF + t] = mean * g;
    }
}

extern "C" void kernel_launch(void* const* d_in, const int* in_sizes, int n_in,
                              void* d_out, int out_size, void* d_ws, size_t ws_size,
                              hipStream_t stream) {
    const float* x          = (const float*)d_in[0];
    const float* weight     = (const float*)d_in[1];
    const float* bias       = (const float*)d_in[2];
    const float* scale_proj = (const float*)d_in[3];
    const float* scale_bias = (const float*)d_in[4];
    float* out = (float*)d_out;

    fused_conv_mfma<<<1024, 256, 0, stream>>>(x, weight, bias,
                                              scale_proj, scale_bias, out);
}